// Round 6
// baseline (798.281 us; speedup 1.0000x reference)
//
#include <hip/hip_runtime.h>
#include <hip/hip_cooperative_groups.h>

namespace cg = cooperative_groups;

#define NNODES 40960
#define NEDGES 81920
#define NG     1024
#define NCOMBO 512

struct P {
    const int *nf, *ef, *src, *dst;
    const float *atom_emb, *bond_emb, *gW1, *gW2, *gW3, *root, *cbias;
    const float *mW1, *mb1, *mW2, *mb2, *mW3, *mb3, *mW4, *mb4, *mW5, *mb5;
    float *x, *out, *h1, *h2, *part, *outv;
    int *cnt, *bstart, *bfill, *cid;
    int2 *ebuf;
};

// ================= phase device functions (grid-stride; any grid size) =========

// ---- node encoder + root init + h1 + cid + cnt-zero ----
__device__ void ph_front(const P& p) {
    __shared__ float xs[4][64];
    __shared__ float etab_s[16];
    const int t = threadIdx.x;
    const int stride = gridDim.x * 256;
    // atom encoder + root transform: 10240 groups of 4 nodes
    {
        const int nn = t >> 6, d = t & 63;
        const int o = t & 31, h = (t >> 5) & 1;
        for (int v = blockIdx.x; v < NNODES / 4; v += gridDim.x) {
            int n = v * 4 + nn;
            const int* nfr = p.nf + n * 9;
            float acc = 0.f;
#pragma unroll
            for (int c = 0; c < 9; ++c) {
                int idx = nfr[c];
                acc += p.atom_emb[((c << 7) + idx) * 64 + d];
            }
            p.x[n * 64 + d] = acc;
            xs[nn][d] = acc;
            __syncthreads();
            float s = h ? 0.f : p.cbias[o];
            int k0 = h * 32;
#pragma unroll
            for (int kq = 0; kq < 8; ++kq) {
                float4 xv = *reinterpret_cast<const float4*>(&xs[nn][k0 + kq * 4]);
                s += xv.x * p.root[(k0 + kq * 4 + 0) * 32 + o];
                s += xv.y * p.root[(k0 + kq * 4 + 1) * 32 + o];
                s += xv.z * p.root[(k0 + kq * 4 + 2) * 32 + o];
                s += xv.w * p.root[(k0 + kq * 4 + 3) * 32 + o];
            }
            s += __shfl_xor(s, 32);
            if (!h) p.out[n * 32 + o] = s;
            __syncthreads();
        }
    }
    // h1[c] = relu(etab[c] @ gW1)
    for (int c = blockIdx.x; c < NCOMBO; c += gridDim.x) {
        if (t < 16) {
            int f0 = c >> 6, f1 = (c >> 3) & 7, f2 = c & 7;
            etab_s[t] = p.bond_emb[f0 * 16 + t] + p.bond_emb[(8 + f1) * 16 + t] +
                        p.bond_emb[(16 + f2) * 16 + t];
        }
        __syncthreads();
        int col = t * 4;
        float4 acc = {0.f, 0.f, 0.f, 0.f};
#pragma unroll
        for (int j = 0; j < 16; ++j) {
            float4 w = *reinterpret_cast<const float4*>(&p.gW1[j * 1024 + col]);
            float e = etab_s[j];
            acc.x += e * w.x; acc.y += e * w.y; acc.z += e * w.z; acc.w += e * w.w;
        }
        acc.x = fmaxf(acc.x, 0.f); acc.y = fmaxf(acc.y, 0.f);
        acc.z = fmaxf(acc.z, 0.f); acc.w = fmaxf(acc.w, 0.f);
        *reinterpret_cast<float4*>(&p.h1[c * 1024 + col]) = acc;
        __syncthreads();
    }
    // cid + cnt zero
    const int gtid = blockIdx.x * 256 + t;
    for (int e = gtid; e < NEDGES; e += stride)
        p.cid[e] = (p.ef[e * 3] << 6) | (p.ef[e * 3 + 1] << 3) | p.ef[e * 3 + 2];
    for (int c = gtid; c < NCOMBO; c += stride) p.cnt[c] = 0;
}

__device__ void ph_hist(const P& p) {
    const int gtid = blockIdx.x * 256 + threadIdx.x;
    for (int e = gtid; e < NEDGES; e += gridDim.x * 256)
        atomicAdd(&p.cnt[p.cid[e]], 1);
}

__device__ void ph_scan(const P& p) {
    __shared__ int ss[256];
    if (blockIdx.x != 0) return;
    const int t = threadIdx.x;
    int a = p.cnt[2 * t], b = p.cnt[2 * t + 1];
    ss[t] = a + b;
    __syncthreads();
    for (int off = 1; off < 256; off <<= 1) {
        int v = (t >= off) ? ss[t - off] : 0;
        __syncthreads();
        ss[t] += v;
        __syncthreads();
    }
    int excl = ss[t] - (a + b);
    p.bstart[2 * t] = excl;     p.bstart[2 * t + 1] = excl + a;
    p.bfill[2 * t] = excl;      p.bfill[2 * t + 1] = excl + a;
    if (t == 255) p.bstart[NCOMBO] = NEDGES;
}

__device__ void ph_scatter(const P& p) {
    const int gtid = blockIdx.x * 256 + threadIdx.x;
    for (int e = gtid; e < NEDGES; e += gridDim.x * 256) {
        int pos = atomicAdd(&p.bfill[p.cid[e]], 1);
        p.ebuf[pos] = make_int2(p.src[e], p.dst[e]);
    }
}

// ---- 64x64-tile split-K GEMM; ntile = nx*ny*nz virtual tiles, grid-stride ----
__device__ void ph_gemm(const float* __restrict__ A, const float* __restrict__ B,
                        float* __restrict__ Cp, int M, int N, int K, int KS,
                        int nx, int ny, int nz) {
    __shared__ float As[16][68];
    __shared__ float Bs[16][68];
    const int t = threadIdx.x;
    const int tx = t & 15, ty = t >> 4;
    const int am = t >> 2, ak = (t & 3) << 2;
    const int bk = t >> 4, bn = (t & 15) << 2;
    const int ntile = nx * ny * nz;
    for (int v = blockIdx.x; v < ntile; v += gridDim.x) {
        const int bx = v % nx, by = (v / nx) % ny, bz = v / (nx * ny);
        const int row0 = by * 64, col0 = bx * 64;
        float acc[4][4] = {};
        const int kb = bz * KS, ke = kb + KS;
        for (int k0 = kb; k0 < ke; k0 += 16) {
            float4 av = *reinterpret_cast<const float4*>(&A[(row0 + am) * K + k0 + ak]);
            float4 bv = *reinterpret_cast<const float4*>(&B[(k0 + bk) * N + col0 + bn]);
            As[ak + 0][am] = av.x;
            As[ak + 1][am] = av.y;
            As[ak + 2][am] = av.z;
            As[ak + 3][am] = av.w;
            *reinterpret_cast<float4*>(&Bs[bk][bn]) = bv;
            __syncthreads();
#pragma unroll
            for (int k = 0; k < 16; ++k) {
                float a[4], b[4];
                *reinterpret_cast<float4*>(a) = *reinterpret_cast<const float4*>(&As[k][ty * 4]);
                *reinterpret_cast<float4*>(b) = *reinterpret_cast<const float4*>(&Bs[k][tx * 4]);
#pragma unroll
                for (int i = 0; i < 4; ++i)
#pragma unroll
                    for (int j = 0; j < 4; ++j) acc[i][j] += a[i] * b[j];
            }
            __syncthreads();
        }
        float* dstp = Cp + (size_t)bz * M * N;
#pragma unroll
        for (int i = 0; i < 4; ++i) {
            float4 vv;
            vv.x = acc[i][0]; vv.y = acc[i][1]; vv.z = acc[i][2]; vv.w = acc[i][3];
            *reinterpret_cast<float4*>(&dstp[(row0 + ty * 4 + i) * N + col0 + tx * 4]) = vv;
        }
    }
}

__device__ void ph_reduce_h2(const P& p) {
    const int gtid = blockIdx.x * 256 + threadIdx.x;
    for (int i4 = gtid * 4; i4 < NCOMBO * 256; i4 += gridDim.x * 1024) {
        float4 acc = *reinterpret_cast<const float4*>(&p.part[i4]);
        for (int z = 1; z < 16; ++z) {
            float4 v = *reinterpret_cast<const float4*>(&p.part[z * (NCOMBO * 256) + i4]);
            acc.x += v.x; acc.y += v.y; acc.z += v.z; acc.w += v.w;
        }
        acc.x = fmaxf(acc.x, 0.f); acc.y = fmaxf(acc.y, 0.f);
        acc.z = fmaxf(acc.z, 0.f); acc.w = fmaxf(acc.w, 0.f);
        *reinterpret_cast<float4*>(&p.h2[i4]) = acc;
    }
}

// ---- bucketed msg; W = part0+part1 (folds gW3 2-way split-K reduce) ----
__device__ void ph_msg(const P& p) {
    __shared__ float Ws[2048];
    __shared__ float xg[64][64];
    __shared__ int2 es[64];
    const int t = threadIdx.x;
    const int o = t & 31;
    for (int c = blockIdx.x; c < NCOMBO; c += gridDim.x) {
        const int beg = p.bstart[c], cnt = p.bstart[c + 1] - beg;
        if (cnt == 0) continue;
        const float* p0 = p.part + (c << 11);
        const float* p1 = p0 + NCOMBO * 2048;
#pragma unroll
        for (int i = 0; i < 8; ++i) {
            int idx = i * 256 + t;
            Ws[idx] = p0[idx] + p1[idx];
        }
        __syncthreads();
        float W[64];
#pragma unroll
        for (int k = 0; k < 64; ++k) W[k] = Ws[(k << 5) | o];
        for (int chunk = 0; chunk < cnt; chunk += 64) {
            int nE = min(64, cnt - chunk);
            if (t < nE) es[t] = p.ebuf[beg + chunk + t];
            __syncthreads();
            for (int i = t; i < nE * 16; i += 256) {
                int r = i >> 4, q = i & 15;
                reinterpret_cast<float4*>(xg[r])[q] =
                    reinterpret_cast<const float4*>(p.x + es[r].x * 64)[q];
            }
            __syncthreads();
            for (int e = t >> 5; e < nE; e += 8) {
                float acc = 0.f;
#pragma unroll
                for (int kq = 0; kq < 16; ++kq) {
                    float4 xv = *reinterpret_cast<const float4*>(&xg[e][kq * 4]);
                    acc += xv.x * W[kq * 4 + 0] + xv.y * W[kq * 4 + 1] +
                           xv.z * W[kq * 4 + 2] + xv.w * W[kq * 4 + 3];
                }
                atomicAdd(&p.out[es[e].y * 32 + o], acc);
            }
            __syncthreads();
        }
    }
}

// ---- fused readout: mW1-partials reduce + mW2..mW5 (2 graphs per block-iter) ----
__device__ void ph_readout(const P& p) {
    __shared__ float f1s[2][256];
    __shared__ float f2s[2][128];
    __shared__ float f3s[2][32];
    __shared__ float f4s[2][8];
    const int t = threadIdx.x;
    const int gg = t >> 7, j = t & 127;
    for (int v = blockIdx.x; v < NG / 2; v += gridDim.x) {
        const int g = v * 2 + gg;
        for (int k = j; k < 256; k += 128) {
            float acc = p.mb1[k];
#pragma unroll
            for (int z = 0; z < 8; ++z) acc += p.part[z * (NG * 256) + g * 256 + k];
            f1s[gg][k] = fmaxf(acc, 0.f);
        }
        __syncthreads();
        {
            float acc = p.mb2[j];
#pragma unroll 8
            for (int k = 0; k < 256; ++k) acc += f1s[gg][k] * p.mW2[k * 128 + j];
            f2s[gg][j] = fmaxf(acc, 0.f);
        }
        __syncthreads();
        if (j < 32) {
            float acc = p.mb3[j];
#pragma unroll 8
            for (int k = 0; k < 128; ++k) acc += f2s[gg][k] * p.mW3[k * 32 + j];
            f3s[gg][j] = fmaxf(acc, 0.f);
        }
        __syncthreads();
        if (j < 8) {
            float acc = p.mb4[j];
#pragma unroll
            for (int k = 0; k < 32; ++k) acc += f3s[gg][k] * p.mW4[k * 8 + j];
            f4s[gg][j] = fmaxf(acc, 0.f);
        }
        __syncthreads();
        if (j == 0) {
            float acc = p.mb5[0];
#pragma unroll
            for (int k = 0; k < 8; ++k) acc += f4s[gg][k] * p.mW5[k];
            p.outv[g] = acc;
        }
        __syncthreads();
    }
}

// ================= cooperative mega-kernel =================
__global__ __launch_bounds__(256) void k_all(P p) {
    cg::grid_group grid = cg::this_grid();
    ph_front(p);
    __threadfence(); grid.sync();
    ph_hist(p);
    __threadfence(); grid.sync();
    ph_scan(p);
    __threadfence(); grid.sync();
    ph_scatter(p);
    __threadfence(); grid.sync();
    ph_gemm(p.h1, p.gW2, p.part, NCOMBO, 256, 1024, 64, 4, 8, 16);
    __threadfence(); grid.sync();
    ph_reduce_h2(p);
    __threadfence(); grid.sync();
    ph_gemm(p.h2, p.gW3, p.part, NCOMBO, 2048, 256, 128, 32, 8, 2);
    __threadfence(); grid.sync();
    ph_msg(p);
    __threadfence(); grid.sync();
    ph_gemm(p.out, p.mW1, p.part, NG, 256, 1280, 160, 4, 16, 8);
    __threadfence(); grid.sync();
    ph_readout(p);
}

// ================= fallback wrappers (ordinary launches) =================
__global__ __launch_bounds__(256) void w_front(P p)   { ph_front(p); }
__global__ __launch_bounds__(256) void w_hist(P p)    { ph_hist(p); }
__global__ __launch_bounds__(256) void w_scan(P p)    { ph_scan(p); }
__global__ __launch_bounds__(256) void w_scatter(P p) { ph_scatter(p); }
__global__ __launch_bounds__(256) void w_gemm1(P p) {
    ph_gemm(p.h1, p.gW2, p.part, NCOMBO, 256, 1024, 64, 4, 8, 16);
}
__global__ __launch_bounds__(256) void w_redh2(P p)   { ph_reduce_h2(p); }
__global__ __launch_bounds__(256) void w_gemm2(P p) {
    ph_gemm(p.h2, p.gW3, p.part, NCOMBO, 2048, 256, 128, 32, 8, 2);
}
__global__ __launch_bounds__(256) void w_msg(P p)     { ph_msg(p); }
__global__ __launch_bounds__(256) void w_gemm3(P p) {
    ph_gemm(p.out, p.mW1, p.part, NG, 256, 1280, 160, 4, 16, 8);
}
__global__ __launch_bounds__(256) void w_readout(P p) { ph_readout(p); }

extern "C" void kernel_launch(void* const* d_in, const int* in_sizes, int n_in,
                              void* d_out, int out_size, void* d_ws, size_t ws_size,
                              hipStream_t stream) {
    P p;
    p.nf       = (const int*)d_in[0];
    p.ef       = (const int*)d_in[1];
    const int* eidx = (const int*)d_in[2];
    p.src = eidx;
    p.dst = eidx + NEDGES;
    p.atom_emb = (const float*)d_in[4];
    p.bond_emb = (const float*)d_in[5];
    p.gW1      = (const float*)d_in[6];
    p.gW2      = (const float*)d_in[7];
    p.gW3      = (const float*)d_in[8];
    p.root     = (const float*)d_in[9];
    p.cbias    = (const float*)d_in[10];
    p.mW1      = (const float*)d_in[11];
    p.mb1      = (const float*)d_in[12];
    p.mW2      = (const float*)d_in[13];
    p.mb2      = (const float*)d_in[14];
    p.mW3      = (const float*)d_in[15];
    p.mb3      = (const float*)d_in[16];
    p.mW4      = (const float*)d_in[17];
    p.mb4      = (const float*)d_in[18];
    p.mW5      = (const float*)d_in[19];
    p.mb5      = (const float*)d_in[20];

    float* ws = (float*)d_ws;
    p.x    = ws;                         // 2621440
    p.out  = p.x + 2621440;              // 1310720
    p.h1   = p.out + 1310720;            // 524288
    p.h2   = p.h1 + 524288;              // 131072
    p.part = p.h2 + 131072;              // 2097152 (8 MB)
    int* ip = (int*)(p.part + 2097152);
    p.cnt    = ip;            ip += NCOMBO;
    p.bstart = ip;            ip += NCOMBO + 1;
    p.bfill  = ip;            ip += NCOMBO;
    p.cid    = ip;            ip += NEDGES;
    p.ebuf   = (int2*)ip;
    p.outv   = (float*)d_out;

    void* args[] = {&p};
    hipError_t err = hipLaunchCooperativeKernel((void*)k_all, dim3(256), dim3(256),
                                                args, 0, stream);
    if (err != hipSuccess) {
        // fallback: same phases as ordinary kernels
        w_front  <<<512, 256, 0, stream>>>(p);
        w_hist   <<<320, 256, 0, stream>>>(p);
        w_scan   <<<1,   256, 0, stream>>>(p);
        w_scatter<<<320, 256, 0, stream>>>(p);
        w_gemm1  <<<512, 256, 0, stream>>>(p);
        w_redh2  <<<128, 256, 0, stream>>>(p);
        w_gemm2  <<<512, 256, 0, stream>>>(p);
        w_msg    <<<512, 256, 0, stream>>>(p);
        w_gemm3  <<<512, 256, 0, stream>>>(p);
        w_readout<<<512, 256, 0, stream>>>(p);
    }
}